// Round 7
// baseline (447.465 us; speedup 1.0000x reference)
//
#include <hip/hip_runtime.h>
#include <math.h>

#define N_QUBITS 4
#define N_LAYERS 6
#define NW (N_LAYERS * N_QUBITS)

// ---------------------------------------------------------------------------
// Prep kernel (1 block): build W (16x16 complex) from the 24 RX gates + CNOT
// rings, form S_q = Re(W^dag Z_q W), contract to the 81-term multilinear table
//   out_q(x) = sum_{t in {I,Z,X}^4} C_q[t] * prod_p (1, cos x_p, sin x_p)[t_p]
// Layout: Ctab[t*4 + q]  (float4 per term t -> one load feeds all 4 outputs).
// Fast trig (__cosf/__sinf): libm cosf is a branchy slow path on this serial
// single-wave phase; accuracy is ~1e-5, far under the 2e-2 threshold.
// ---------------------------------------------------------------------------
__global__ __launch_bounds__(256) void qprep_kernel(
    const float* __restrict__ weights, float* __restrict__ Ctab)
{
    __shared__ float Wr[16][16];
    __shared__ float Wi[16][16];
    __shared__ float S[4][16][16];
    __shared__ float wc[NW], ws[NW];
    const int tid = threadIdx.x;
    if (tid < NW) {
        float t = weights[tid] * 0.5f;
        wc[tid] = __cosf(t);
        ws[tid] = __sinf(t);
    }
    __syncthreads();

    // Phase 1: threads 0..15 build column `tid` of W
    if (tid < 16) {
        float re[16], im[16];
#pragma unroll
        for (int k = 0; k < 16; ++k) { re[k] = (k == tid) ? 1.f : 0.f; im[k] = 0.f; }
#pragma unroll 1
        for (int l = 0; l < N_LAYERS; ++l) {
#pragma unroll
            for (int q = 0; q < 4; ++q) {
                const float ct = wc[l * 4 + q], sn = ws[l * 4 + q];
                const int mask = 8 >> q;
#pragma unroll
                for (int idx = 0; idx < 16; ++idx) {
                    if (idx & mask) continue;
                    const int j = idx | mask;
                    float r0 = re[idx], u0 = im[idx], r1 = re[j], u1 = im[j];
                    re[idx] = ct * r0 + sn * u1; im[idx] = ct * u0 - sn * r1;
                    re[j]   = ct * r1 + sn * u0; im[j]   = ct * u1 - sn * r0;
                }
            }
#pragma unroll
            for (int q = 0; q < 4; ++q) {
                const int cm = 8 >> q, tm = 8 >> ((q + 1) & 3);
#pragma unroll
                for (int idx = 0; idx < 16; ++idx) {
                    if ((idx & cm) && !(idx & tm)) {
                        const int j = idx | tm;
                        float t0 = re[idx]; re[idx] = re[j]; re[j] = t0;
                        float t1 = im[idx]; im[idx] = im[j]; im[j] = t1;
                    }
                }
            }
        }
#pragma unroll
        for (int k = 0; k < 16; ++k) { Wr[k][tid] = re[k]; Wi[k][tid] = im[k]; }
    }
    __syncthreads();

    // Phase 2: thread (i,j): S_q[i][j] = sum_k z_q(k) Re(W[k,i] conj(W[k,j]))
    {
        const int i = tid >> 4, j = tid & 15;
        float acc0 = 0.f, acc1 = 0.f, acc2 = 0.f, acc3 = 0.f;
#pragma unroll
        for (int k = 0; k < 16; ++k) {
            const float prod = Wr[k][i] * Wr[k][j] + Wi[k][i] * Wi[k][j];
            acc0 += (k & 8) ? -prod : prod;
            acc1 += (k & 4) ? -prod : prod;
            acc2 += (k & 2) ? -prod : prod;
            acc3 += (k & 1) ? -prod : prod;
        }
        S[0][i][j] = acc0; S[1][i][j] = acc1; S[2][i][j] = acc2; S[3][i][j] = acc3;
    }
    __syncthreads();

    // Phase 3: C_q[t] = (1/16) sum_i (-1)^popc(i&zm) S_q[i][i^xm]
    if (tid < 81) {
        const int t1 = tid / 27, t2 = (tid / 9) % 3, t3 = (tid / 3) % 3, t4 = tid % 3;
        int zm = 0, xm = 0;
        if (t1 == 1) zm |= 8; else if (t1 == 2) xm |= 8;
        if (t2 == 1) zm |= 4; else if (t2 == 2) xm |= 4;
        if (t3 == 1) zm |= 2; else if (t3 == 2) xm |= 2;
        if (t4 == 1) zm |= 1; else if (t4 == 2) xm |= 1;
#pragma unroll
        for (int q = 0; q < 4; ++q) {
            float acc = 0.f;
#pragma unroll
            for (int i = 0; i < 16; ++i) {
                const float v = S[q][i][i ^ xm];
                acc += (__popc(i & zm) & 1) ? -v : v;
            }
            Ctab[tid * 4 + q] = acc * 0.0625f;   // float4-per-term layout
        }
    }
}

// ---------------------------------------------------------------------------
// Main kernel: out4 = sum_i u9[i] * ( sum_j C[i*9+j] * w9[j] ),
//   u9[t1*3+t2] = v0[t1]*v1[t2], w9[t3*3+t4] = v2[t3]*v3[t4],
//   vp = {1, cos x_p, sin x_p}.
// Coefficients staged ONCE per block in LDS (81 x float4 = 1.3 KB); inner
// reads are same-address ds_read_b128 broadcasts on the DS pipe (overlaps
// VALU; removes the 81 per-thread VMEM-issue ops that gated R5/R6).
// M=2 samples/thread in registers halves per-sample DS issue; live set
// ~75 floats (R4's spill was at M=4 / ~200 live). Block covers 512 samples.
// ---------------------------------------------------------------------------
__global__ __launch_bounds__(256, 4) void qeval_kernel(
    const float* __restrict__ x, const float* __restrict__ Ctab,
    float* __restrict__ out, int B)
{
    __shared__ float4 Cs[81];
    const int tid = threadIdx.x;
    if (tid < 81) Cs[tid] = reinterpret_cast<const float4*>(Ctab)[tid];
    __syncthreads();

    const int b0 = blockIdx.x * 512 + tid;        // sample for m=0
    const int b1 = b0 + 256;                      // sample for m=1

    float u9[2][9], w9[2][9];
#pragma unroll
    for (int m = 0; m < 2; ++m) {
        const int b = (m == 0) ? b0 : b1;
        float4 xv = (b < B) ? reinterpret_cast<const float4*>(x)[b]
                            : make_float4(0.f, 0.f, 0.f, 0.f);
        const float c0 = __cosf(xv.x), s0 = __sinf(xv.x);
        const float c1 = __cosf(xv.y), s1 = __sinf(xv.y);
        const float c2 = __cosf(xv.z), s2 = __sinf(xv.z);
        const float c3 = __cosf(xv.w), s3 = __sinf(xv.w);
        u9[m][0] = 1.f; u9[m][1] = c1;      u9[m][2] = s1;
        u9[m][3] = c0;  u9[m][4] = c0 * c1; u9[m][5] = c0 * s1;
        u9[m][6] = s0;  u9[m][7] = s0 * c1; u9[m][8] = s0 * s1;
        w9[m][0] = 1.f; w9[m][1] = c3;      w9[m][2] = s3;
        w9[m][3] = c2;  w9[m][4] = c2 * c3; w9[m][5] = c2 * s3;
        w9[m][6] = s2;  w9[m][7] = s2 * c3; w9[m][8] = s2 * s3;
    }

    float4 o[2];
    o[0] = make_float4(0.f, 0.f, 0.f, 0.f);
    o[1] = make_float4(0.f, 0.f, 0.f, 0.f);

#pragma unroll
    for (int i = 0; i < 9; ++i) {
        float4 t0 = make_float4(0.f, 0.f, 0.f, 0.f);
        float4 t1 = make_float4(0.f, 0.f, 0.f, 0.f);
#pragma unroll
        for (int j = 0; j < 9; ++j) {
            const float4 c = Cs[i * 9 + j];   // LDS broadcast (same addr)
            const float wa = w9[0][j], wb = w9[1][j];
            t0.x = fmaf(c.x, wa, t0.x); t0.y = fmaf(c.y, wa, t0.y);
            t0.z = fmaf(c.z, wa, t0.z); t0.w = fmaf(c.w, wa, t0.w);
            t1.x = fmaf(c.x, wb, t1.x); t1.y = fmaf(c.y, wb, t1.y);
            t1.z = fmaf(c.z, wb, t1.z); t1.w = fmaf(c.w, wb, t1.w);
        }
        const float ua = u9[0][i], ub = u9[1][i];
        o[0].x = fmaf(t0.x, ua, o[0].x); o[0].y = fmaf(t0.y, ua, o[0].y);
        o[0].z = fmaf(t0.z, ua, o[0].z); o[0].w = fmaf(t0.w, ua, o[0].w);
        o[1].x = fmaf(t1.x, ub, o[1].x); o[1].y = fmaf(t1.y, ub, o[1].y);
        o[1].z = fmaf(t1.z, ub, o[1].z); o[1].w = fmaf(t1.w, ub, o[1].w);
    }

    if (b0 < B) reinterpret_cast<float4*>(out)[b0] = o[0];
    if (b1 < B) reinterpret_cast<float4*>(out)[b1] = o[1];
}

extern "C" void kernel_launch(void* const* d_in, const int* in_sizes, int n_in,
                              void* d_out, int out_size, void* d_ws, size_t ws_size,
                              hipStream_t stream) {
    const float* x = (const float*)d_in[0];
    const float* weights = (const float*)d_in[1];
    float* out = (float*)d_out;
    float* Ctab = (float*)d_ws;   // 324 floats, float4-per-term
    const int B = in_sizes[0] / 4;

    qprep_kernel<<<1, 256, 0, stream>>>(weights, Ctab);

    const int grid = (B + 511) / 512;   // 512 samples per block (M=2)
    qeval_kernel<<<grid, 256, 0, stream>>>(x, Ctab, out, B);
}

// Round 8
// 80.613 us; speedup vs baseline: 5.5508x; 5.5508x over previous
//
#include <hip/hip_runtime.h>
#include <math.h>

#define N_QUBITS 4
#define N_LAYERS 6
#define NW (N_LAYERS * N_QUBITS)

// ---------------------------------------------------------------------------
// Prep kernel (1 block): build W (16x16 complex) from the 24 RX gates + CNOT
// rings, form S_q = Re(W^dag Z_q W), contract to the 81-term multilinear table
//   out_q(x) = sum_{t in {I,Z,X}^4} C_q[t] * prod_p (1, cos x_p, sin x_p)[t_p]
// Layout: Ctab[t*4 + q]  (float4 per term t -> one load feeds all 4 outputs).
// ---------------------------------------------------------------------------
__global__ __launch_bounds__(256) void qprep_kernel(
    const float* __restrict__ weights, float* __restrict__ Ctab)
{
    __shared__ float Wr[16][16];
    __shared__ float Wi[16][16];
    __shared__ float S[4][16][16];
    __shared__ float wc[NW], ws[NW];
    const int tid = threadIdx.x;
    if (tid < NW) {
        float t = weights[tid] * 0.5f;
        wc[tid] = __cosf(t);
        ws[tid] = __sinf(t);
    }
    __syncthreads();

    // Phase 1: threads 0..15 build column `tid` of W
    if (tid < 16) {
        float re[16], im[16];
#pragma unroll
        for (int k = 0; k < 16; ++k) { re[k] = (k == tid) ? 1.f : 0.f; im[k] = 0.f; }
#pragma unroll 1
        for (int l = 0; l < N_LAYERS; ++l) {
#pragma unroll
            for (int q = 0; q < 4; ++q) {
                const float ct = wc[l * 4 + q], sn = ws[l * 4 + q];
                const int mask = 8 >> q;
#pragma unroll
                for (int idx = 0; idx < 16; ++idx) {
                    if (idx & mask) continue;
                    const int j = idx | mask;
                    float r0 = re[idx], u0 = im[idx], r1 = re[j], u1 = im[j];
                    re[idx] = ct * r0 + sn * u1; im[idx] = ct * u0 - sn * r1;
                    re[j]   = ct * r1 + sn * u0; im[j]   = ct * u1 - sn * r0;
                }
            }
#pragma unroll
            for (int q = 0; q < 4; ++q) {
                const int cm = 8 >> q, tm = 8 >> ((q + 1) & 3);
#pragma unroll
                for (int idx = 0; idx < 16; ++idx) {
                    if ((idx & cm) && !(idx & tm)) {
                        const int j = idx | tm;
                        float t0 = re[idx]; re[idx] = re[j]; re[j] = t0;
                        float t1 = im[idx]; im[idx] = im[j]; im[j] = t1;
                    }
                }
            }
        }
#pragma unroll
        for (int k = 0; k < 16; ++k) { Wr[k][tid] = re[k]; Wi[k][tid] = im[k]; }
    }
    __syncthreads();

    // Phase 2: thread (i,j): S_q[i][j] = sum_k z_q(k) Re(W[k,i] conj(W[k,j]))
    {
        const int i = tid >> 4, j = tid & 15;
        float acc0 = 0.f, acc1 = 0.f, acc2 = 0.f, acc3 = 0.f;
#pragma unroll
        for (int k = 0; k < 16; ++k) {
            const float prod = Wr[k][i] * Wr[k][j] + Wi[k][i] * Wi[k][j];
            acc0 += (k & 8) ? -prod : prod;
            acc1 += (k & 4) ? -prod : prod;
            acc2 += (k & 2) ? -prod : prod;
            acc3 += (k & 1) ? -prod : prod;
        }
        S[0][i][j] = acc0; S[1][i][j] = acc1; S[2][i][j] = acc2; S[3][i][j] = acc3;
    }
    __syncthreads();

    // Phase 3: C_q[t] = (1/16) sum_i (-1)^popc(i&zm) S_q[i][i^xm]
    if (tid < 81) {
        const int t1 = tid / 27, t2 = (tid / 9) % 3, t3 = (tid / 3) % 3, t4 = tid % 3;
        int zm = 0, xm = 0;
        if (t1 == 1) zm |= 8; else if (t1 == 2) xm |= 8;
        if (t2 == 1) zm |= 4; else if (t2 == 2) xm |= 4;
        if (t3 == 1) zm |= 2; else if (t3 == 2) xm |= 2;
        if (t4 == 1) zm |= 1; else if (t4 == 2) xm |= 1;
#pragma unroll
        for (int q = 0; q < 4; ++q) {
            float acc = 0.f;
#pragma unroll
            for (int i = 0; i < 16; ++i) {
                const float v = S[q][i][i ^ xm];
                acc += (__popc(i & zm) & 1) ? -v : v;
            }
            Ctab[tid * 4 + q] = acc * 0.0625f;   // float4-per-term layout
        }
    }
}

// ---------------------------------------------------------------------------
// Main kernel: out4 = sum_i u9[i] * ( sum_j C4[i*9+j] * w9[j] ).
// KEY CHANGE vs R6: no early return — index is CLAMPED so control flow stays
// wave-uniform. Uniform CF lets the compiler promote the 81 thread-invariant
// float4 coefficient loads to s_load (SGPR broadcast, ~324 dwords/wave)
// instead of per-lane vector loads whose 1 KiB/instr broadcast returns were
// L1-return-bandwidth bound (~650 cyc/wave -> the observed ~18 us).
// Every inner op is v_fma(dst, sgpr, vgpr, vgpr): exactly 1 SGPR operand.
// 1D arrays only (R7's 2D arrays fell to scratch: 1.3 GB of HBM traffic).
// ---------------------------------------------------------------------------
__global__ __launch_bounds__(256, 6) void qeval_kernel(
    const float* __restrict__ x, const float* __restrict__ Ctab,
    float* __restrict__ out, int B)
{
    int b = blockIdx.x * 256 + threadIdx.x;
    b = (b < B) ? b : (B - 1);   // clamp, not return: keep CF wave-uniform
                                 // (B % 256 == 0 in practice -> never taken;
                                 // if taken, duplicate writes of same value)

    const float4 xv = reinterpret_cast<const float4*>(x)[b];
    const float c0 = __cosf(xv.x), s0 = __sinf(xv.x);
    const float c1 = __cosf(xv.y), s1 = __sinf(xv.y);
    const float c2 = __cosf(xv.z), s2 = __sinf(xv.z);
    const float c3 = __cosf(xv.w), s3 = __sinf(xv.w);

    // u9[t1*3+t2] = v0[t1]*v1[t2];  w9[t3*3+t4] = v2[t3]*v3[t4]
    float u9[9], w9[9];
    u9[0] = 1.f;  u9[1] = c1;      u9[2] = s1;
    u9[3] = c0;   u9[4] = c0 * c1; u9[5] = c0 * s1;
    u9[6] = s0;   u9[7] = s0 * c1; u9[8] = s0 * s1;
    w9[0] = 1.f;  w9[1] = c3;      w9[2] = s3;
    w9[3] = c2;   w9[4] = c2 * c3; w9[5] = c2 * s3;
    w9[6] = s2;   w9[7] = s2 * c3; w9[8] = s2 * s3;

    const float4* __restrict__ C4 = reinterpret_cast<const float4*>(Ctab);

    float4 o = make_float4(0.f, 0.f, 0.f, 0.f);
#pragma unroll
    for (int i = 0; i < 9; ++i) {
        float4 t = make_float4(0.f, 0.f, 0.f, 0.f);
#pragma unroll
        for (int j = 0; j < 9; ++j) {
            const float4 c = C4[i * 9 + j];   // uniform + uniform CF -> s_load
            const float w = w9[j];
            t.x = fmaf(c.x, w, t.x);
            t.y = fmaf(c.y, w, t.y);
            t.z = fmaf(c.z, w, t.z);
            t.w = fmaf(c.w, w, t.w);
        }
        const float u = u9[i];
        o.x = fmaf(t.x, u, o.x);
        o.y = fmaf(t.y, u, o.y);
        o.z = fmaf(t.z, u, o.z);
        o.w = fmaf(t.w, u, o.w);
    }

    reinterpret_cast<float4*>(out)[b] = o;
}

extern "C" void kernel_launch(void* const* d_in, const int* in_sizes, int n_in,
                              void* d_out, int out_size, void* d_ws, size_t ws_size,
                              hipStream_t stream) {
    const float* x = (const float*)d_in[0];
    const float* weights = (const float*)d_in[1];
    float* out = (float*)d_out;
    float* Ctab = (float*)d_ws;   // 324 floats, float4-per-term
    const int B = in_sizes[0] / 4;

    qprep_kernel<<<1, 256, 0, stream>>>(weights, Ctab);

    const int grid = (B + 255) / 256;
    qeval_kernel<<<grid, 256, 0, stream>>>(x, Ctab, out, B);
}

// Round 9
// 80.516 us; speedup vs baseline: 5.5574x; 1.0012x over previous
//
#include <hip/hip_runtime.h>
#include <math.h>
#include <stdint.h>

#define N_QUBITS 4
#define N_LAYERS 6
#define NW (N_LAYERS * N_QUBITS)

// POD 4-float vector (no C++ ctors -> safe across address spaces)
typedef float vfloat4 __attribute__((ext_vector_type(4)));

// ---------------------------------------------------------------------------
// Prep kernel (1 block): build W (16x16 complex) from the 24 RX gates + CNOT
// rings, form S_q = Re(W^dag Z_q W), contract to the 81-term multilinear table
//   out_q(x) = sum_{t in {I,Z,X}^4} C_q[t] * prod_p (1, cos x_p, sin x_p)[t_p]
// Layout: Ctab[t*4 + q]  (float4 per term t -> one load feeds all 4 outputs).
// (unchanged from R8 — single-variable experiment)
// ---------------------------------------------------------------------------
__global__ __launch_bounds__(256) void qprep_kernel(
    const float* __restrict__ weights, float* __restrict__ Ctab)
{
    __shared__ float Wr[16][16];
    __shared__ float Wi[16][16];
    __shared__ float S[4][16][16];
    __shared__ float wc[NW], ws[NW];
    const int tid = threadIdx.x;
    if (tid < NW) {
        float t = weights[tid] * 0.5f;
        wc[tid] = __cosf(t);
        ws[tid] = __sinf(t);
    }
    __syncthreads();

    // Phase 1: threads 0..15 build column `tid` of W
    if (tid < 16) {
        float re[16], im[16];
#pragma unroll
        for (int k = 0; k < 16; ++k) { re[k] = (k == tid) ? 1.f : 0.f; im[k] = 0.f; }
#pragma unroll 1
        for (int l = 0; l < N_LAYERS; ++l) {
#pragma unroll
            for (int q = 0; q < 4; ++q) {
                const float ct = wc[l * 4 + q], sn = ws[l * 4 + q];
                const int mask = 8 >> q;
#pragma unroll
                for (int idx = 0; idx < 16; ++idx) {
                    if (idx & mask) continue;
                    const int j = idx | mask;
                    float r0 = re[idx], u0 = im[idx], r1 = re[j], u1 = im[j];
                    re[idx] = ct * r0 + sn * u1; im[idx] = ct * u0 - sn * r1;
                    re[j]   = ct * r1 + sn * u0; im[j]   = ct * u1 - sn * r0;
                }
            }
#pragma unroll
            for (int q = 0; q < 4; ++q) {
                const int cm = 8 >> q, tm = 8 >> ((q + 1) & 3);
#pragma unroll
                for (int idx = 0; idx < 16; ++idx) {
                    if ((idx & cm) && !(idx & tm)) {
                        const int j = idx | tm;
                        float t0 = re[idx]; re[idx] = re[j]; re[j] = t0;
                        float t1 = im[idx]; im[idx] = im[j]; im[j] = t1;
                    }
                }
            }
        }
#pragma unroll
        for (int k = 0; k < 16; ++k) { Wr[k][tid] = re[k]; Wi[k][tid] = im[k]; }
    }
    __syncthreads();

    // Phase 2: thread (i,j): S_q[i][j] = sum_k z_q(k) Re(W[k,i] conj(W[k,j]))
    {
        const int i = tid >> 4, j = tid & 15;
        float acc0 = 0.f, acc1 = 0.f, acc2 = 0.f, acc3 = 0.f;
#pragma unroll
        for (int k = 0; k < 16; ++k) {
            const float prod = Wr[k][i] * Wr[k][j] + Wi[k][i] * Wi[k][j];
            acc0 += (k & 8) ? -prod : prod;
            acc1 += (k & 4) ? -prod : prod;
            acc2 += (k & 2) ? -prod : prod;
            acc3 += (k & 1) ? -prod : prod;
        }
        S[0][i][j] = acc0; S[1][i][j] = acc1; S[2][i][j] = acc2; S[3][i][j] = acc3;
    }
    __syncthreads();

    // Phase 3: C_q[t] = (1/16) sum_i (-1)^popc(i&zm) S_q[i][i^xm]
    if (tid < 81) {
        const int t1 = tid / 27, t2 = (tid / 9) % 3, t3 = (tid / 3) % 3, t4 = tid % 3;
        int zm = 0, xm = 0;
        if (t1 == 1) zm |= 8; else if (t1 == 2) xm |= 8;
        if (t2 == 1) zm |= 4; else if (t2 == 2) xm |= 4;
        if (t3 == 1) zm |= 2; else if (t3 == 2) xm |= 2;
        if (t4 == 1) zm |= 1; else if (t4 == 2) xm |= 1;
#pragma unroll
        for (int q = 0; q < 4; ++q) {
            float acc = 0.f;
#pragma unroll
            for (int i = 0; i < 16; ++i) {
                const float v = S[q][i][i ^ xm];
                acc += (__popc(i & zm) & 1) ? -v : v;
            }
            Ctab[tid * 4 + q] = acc * 0.0625f;   // float4-per-term layout
        }
    }
}

// ---------------------------------------------------------------------------
// Main kernel: out4 = sum_i u9[i] * ( sum_j C4[i*9+j] * w9[j] ).
// KEY CHANGE vs R8: coefficient table read through the CONSTANT address
// space (4). Uniform-address AS(4) loads compile to s_load_dwordx4 — 16 B
// per WAVE into SGPRs, then v_fma broadcasts the SGPR operand for free.
// This removes the 83 KB/wave per-lane broadcast return traffic (81 float4
// x 64 lanes through L1) that pinned qeval at ~18 us across R2/R5/R6/R8.
// ---------------------------------------------------------------------------
__global__ __launch_bounds__(256, 6) void qeval_kernel(
    const float* __restrict__ x, const float* __restrict__ Ctab,
    float* __restrict__ out, int B)
{
    int b = blockIdx.x * 256 + threadIdx.x;
    b = (b < B) ? b : (B - 1);   // clamp: wave-uniform control flow

    const float4 xv = reinterpret_cast<const float4*>(x)[b];
    const float c0 = __cosf(xv.x), s0 = __sinf(xv.x);
    const float c1 = __cosf(xv.y), s1 = __sinf(xv.y);
    const float c2 = __cosf(xv.z), s2 = __sinf(xv.z);
    const float c3 = __cosf(xv.w), s3 = __sinf(xv.w);

    // u9[t1*3+t2] = v0[t1]*v1[t2];  w9[t3*3+t4] = v2[t3]*v3[t4]
    float u9[9], w9[9];
    u9[0] = 1.f;  u9[1] = c1;      u9[2] = s1;
    u9[3] = c0;   u9[4] = c0 * c1; u9[5] = c0 * s1;
    u9[6] = s0;   u9[7] = s0 * c1; u9[8] = s0 * s1;
    w9[0] = 1.f;  w9[1] = c3;      w9[2] = s3;
    w9[3] = c2;   w9[4] = c2 * c3; w9[5] = c2 * s3;
    w9[6] = s2;   w9[7] = s2 * c3; w9[8] = s2 * s3;

    // Constant-address-space view of the table -> scalar (s_load) path.
    const __attribute__((address_space(4))) vfloat4* Cc =
        (const __attribute__((address_space(4))) vfloat4*)(unsigned long long)Ctab;

    float4 o = make_float4(0.f, 0.f, 0.f, 0.f);
#pragma unroll
    for (int i = 0; i < 9; ++i) {
        float4 t = make_float4(0.f, 0.f, 0.f, 0.f);
#pragma unroll
        for (int j = 0; j < 9; ++j) {
            const vfloat4 c = Cc[i * 9 + j];   // uniform AS(4) -> s_load_dwordx4
            const float w = w9[j];
            t.x = fmaf(c.x, w, t.x);
            t.y = fmaf(c.y, w, t.y);
            t.z = fmaf(c.z, w, t.z);
            t.w = fmaf(c.w, w, t.w);
        }
        const float u = u9[i];
        o.x = fmaf(t.x, u, o.x);
        o.y = fmaf(t.y, u, o.y);
        o.z = fmaf(t.z, u, o.z);
        o.w = fmaf(t.w, u, o.w);
    }

    reinterpret_cast<float4*>(out)[b] = o;
}

extern "C" void kernel_launch(void* const* d_in, const int* in_sizes, int n_in,
                              void* d_out, int out_size, void* d_ws, size_t ws_size,
                              hipStream_t stream) {
    const float* x = (const float*)d_in[0];
    const float* weights = (const float*)d_in[1];
    float* out = (float*)d_out;
    float* Ctab = (float*)d_ws;   // 324 floats, float4-per-term
    const int B = in_sizes[0] / 4;

    qprep_kernel<<<1, 256, 0, stream>>>(weights, Ctab);

    const int grid = (B + 255) / 256;
    qeval_kernel<<<grid, 256, 0, stream>>>(x, Ctab, out, B);
}